// Round 2
// baseline (291.259 us; speedup 1.0000x reference)
//
#include <hip/hip_runtime.h>
#include <hip/hip_bf16.h>

#define NNODES 8192
#define NEDGES 262144
#define FDIM 256
#define NNOUT 67108864L   // 8192*8192

// ---------------- graph preprocessing ----------------

__global__ __launch_bounds__(256) void zero_kernel(int* __restrict__ p, int n) {
  int i = blockIdx.x * 256 + threadIdx.x;
  if (i < n) p[i] = 0;
}

__global__ __launch_bounds__(256) void deg_kernel(const int* __restrict__ src, const int* __restrict__ dst,
                                                  int* __restrict__ out_deg, int* __restrict__ in_deg) {
  int e = blockIdx.x * 256 + threadIdx.x;
  if (e < NEDGES) {
    atomicAdd(&out_deg[src[e]], 1);
    atomicAdd(&in_deg[dst[e]], 1);
  }
}

__global__ __launch_bounds__(256) void norm_kernel(const int* __restrict__ out_deg, const int* __restrict__ in_deg,
                                                   float* __restrict__ norm_src, float* __restrict__ norm_dst) {
  int i = blockIdx.x * 256 + threadIdx.x;
  if (i < NNODES) {
    int od = out_deg[i]; if (od < 1) od = 1;
    int id = in_deg[i]; if (id < 1) id = 1;
    norm_src[i] = rsqrtf((float)od);
    norm_dst[i] = rsqrtf((float)id);
  }
}

// single block, 256 threads, scans in_deg[8192] -> row_ptr[8193], cursor = row starts
__global__ __launch_bounds__(256) void scan_kernel(const int* __restrict__ in_deg, int* __restrict__ row_ptr,
                                                   int* __restrict__ cursor) {
  __shared__ int partial[256];
  int t = threadIdx.x;
  int base = t * 32;
  int local[32];
  int s = 0;
#pragma unroll
  for (int i = 0; i < 32; ++i) { local[i] = in_deg[base + i]; s += local[i]; }
  partial[t] = s;
  __syncthreads();
  for (int off = 1; off < 256; off <<= 1) {
    int v = (t >= off) ? partial[t - off] : 0;
    __syncthreads();
    partial[t] += v;
    __syncthreads();
  }
  int run = (t == 0) ? 0 : partial[t - 1];
  if (t == 0) row_ptr[0] = 0;
#pragma unroll
  for (int i = 0; i < 32; ++i) {
    cursor[base + i] = run;
    run += local[i];
    row_ptr[base + i + 1] = run;
  }
}

__global__ __launch_bounds__(256) void scatter_kernel(const int* __restrict__ src, const int* __restrict__ dst,
                                                      int* __restrict__ cursor, int* __restrict__ csr) {
  int e = blockIdx.x * 256 + threadIdx.x;
  if (e < NEDGES) {
    int d = dst[e];
    int pos = atomicAdd(&cursor[d], 1);
    csr[pos] = src[e];
  }
}

// ---------------- propagation: out[v] = norm_dst[v] * sum_{e: dst=v} x[src_e]*norm_src[src_e] ----------------

__global__ __launch_bounds__(256) void propagate_kernel(const float* __restrict__ x, float* __restrict__ out,
                                                        const int* __restrict__ row_ptr, const int* __restrict__ csr,
                                                        const float* __restrict__ norm_src,
                                                        const float* __restrict__ norm_dst) {
  int v = blockIdx.x;
  int j = threadIdx.x;
  int beg = row_ptr[v], end = row_ptr[v + 1];
  float acc = 0.f;
  for (int e = beg; e < end; ++e) {
    int s = csr[e];
    float w = norm_src[s];
    acc = fmaf(x[s * FDIM + j], w, acc);
  }
  out[v * FDIM + j] = acc * norm_dst[v];
}

// ---------------- GEMM: C = relu(A@B + bias), A[8192][256], B[256][256] ----------------

__global__ __launch_bounds__(256) void gemm_bias_relu(const float* __restrict__ A, const float* __restrict__ B,
                                                      const float* __restrict__ bias, float* __restrict__ C) {
  __shared__ __align__(16) float As[64][68];
  __shared__ __align__(16) float Bs[64][68];
  int tid = threadIdx.x;
  int tx = tid & 15, ty = tid >> 4;
  int rowBase = blockIdx.x * 64;
  int colBase = blockIdx.y * 64;
  float acc[4][4] = {};
  for (int kb = 0; kb < 256; kb += 64) {
    {
      int m = tid >> 2;
      int k0 = (tid & 3) * 16;
      const float* s0 = A + (rowBase + m) * 256 + kb + k0;
#pragma unroll
      for (int j = 0; j < 4; ++j) {
        float4 v = *(const float4*)(s0 + 4 * j);
        As[k0 + 4 * j + 0][m] = v.x;
        As[k0 + 4 * j + 1][m] = v.y;
        As[k0 + 4 * j + 2][m] = v.z;
        As[k0 + 4 * j + 3][m] = v.w;
      }
      int k = tid >> 2;
      int c0 = (tid & 3) * 16;
      const float* s1 = B + (kb + k) * 256 + colBase + c0;
#pragma unroll
      for (int j = 0; j < 4; ++j)
        *(float4*)&Bs[k][c0 + 4 * j] = *(const float4*)(s1 + 4 * j);
    }
    __syncthreads();
#pragma unroll 8
    for (int kk = 0; kk < 64; ++kk) {
      float4 av = *(const float4*)&As[kk][4 * ty];
      float4 bv = *(const float4*)&Bs[kk][4 * tx];
      float a[4] = {av.x, av.y, av.z, av.w};
      float b[4] = {bv.x, bv.y, bv.z, bv.w};
#pragma unroll
      for (int i = 0; i < 4; ++i)
#pragma unroll
        for (int j = 0; j < 4; ++j) acc[i][j] = fmaf(a[i], b[j], acc[i][j]);
    }
    __syncthreads();
  }
  float4 bv = *(const float4*)(bias + colBase + 4 * tx);
  float bb[4] = {bv.x, bv.y, bv.z, bv.w};
#pragma unroll
  for (int i = 0; i < 4; ++i) {
    int r = rowBase + 4 * ty + i;
    float4 o;
    o.x = fmaxf(acc[i][0] + bb[0], 0.f);
    o.y = fmaxf(acc[i][1] + bb[1], 0.f);
    o.z = fmaxf(acc[i][2] + bb[2], 0.f);
    o.w = fmaxf(acc[i][3] + bb[3], 0.f);
    *(float4*)&C[r * 256 + colBase + 4 * tx] = o;
  }
}

// ---------------- fused mean/log_std GEMM: [8192,256] x [256,64] ----------------
// cols 0..31 from W2[:, :32] (+b2), cols 32..63 from W3 (+b3); relu; split outputs

__global__ __launch_bounds__(256) void gemm_z(const float* __restrict__ A, const float* __restrict__ W2,
                                              const float* __restrict__ b2, const float* __restrict__ W3,
                                              const float* __restrict__ b3, float* __restrict__ mean32,
                                              float* __restrict__ lstd) {
  __shared__ __align__(16) float As[64][68];
  __shared__ __align__(16) float Bs[64][68];
  int tid = threadIdx.x;
  int tx = tid & 15, ty = tid >> 4;
  int rowBase = blockIdx.x * 64;
  float acc[4][4] = {};
  for (int kb = 0; kb < 256; kb += 64) {
    {
      int m = tid >> 2;
      int k0 = (tid & 3) * 16;
      const float* s0 = A + (rowBase + m) * 256 + kb + k0;
#pragma unroll
      for (int j = 0; j < 4; ++j) {
        float4 v = *(const float4*)(s0 + 4 * j);
        As[k0 + 4 * j + 0][m] = v.x;
        As[k0 + 4 * j + 1][m] = v.y;
        As[k0 + 4 * j + 2][m] = v.z;
        As[k0 + 4 * j + 3][m] = v.w;
      }
      int k = tid >> 2;
      int c0 = (tid & 3) * 16;
      const float* s1 = (c0 < 32) ? (W2 + (kb + k) * 256 + c0) : (W3 + (kb + k) * 32 + (c0 - 32));
#pragma unroll
      for (int j = 0; j < 4; ++j)
        *(float4*)&Bs[k][c0 + 4 * j] = *(const float4*)(s1 + 4 * j);
    }
    __syncthreads();
#pragma unroll 8
    for (int kk = 0; kk < 64; ++kk) {
      float4 av = *(const float4*)&As[kk][4 * ty];
      float4 bv = *(const float4*)&Bs[kk][4 * tx];
      float a[4] = {av.x, av.y, av.z, av.w};
      float b[4] = {bv.x, bv.y, bv.z, bv.w};
#pragma unroll
      for (int i = 0; i < 4; ++i)
#pragma unroll
        for (int j = 0; j < 4; ++j) acc[i][j] = fmaf(a[i], b[j], acc[i][j]);
    }
    __syncthreads();
  }
  int c = 4 * tx;
  bool isMean = (c < 32);
  int cc = isMean ? c : (c - 32);
  const float* bp = isMean ? (b2 + cc) : (b3 + cc);
  float* dp = isMean ? mean32 : lstd;
  float4 bv = *(const float4*)bp;
  float bb[4] = {bv.x, bv.y, bv.z, bv.w};
#pragma unroll
  for (int i = 0; i < 4; ++i) {
    int r = rowBase + 4 * ty + i;
    float4 o;
    o.x = fmaxf(acc[i][0] + bb[0], 0.f);
    o.y = fmaxf(acc[i][1] + bb[1], 0.f);
    o.z = fmaxf(acc[i][2] + bb[2], 0.f);
    o.w = fmaxf(acc[i][3] + bb[3], 0.f);
    *(float4*)&dp[r * 32 + cc] = o;
  }
}

__global__ __launch_bounds__(256) void z_combine(const float* __restrict__ mean32, const float* __restrict__ lstd,
                                                 const float* __restrict__ noise, float* __restrict__ z) {
  int i = blockIdx.x * 256 + threadIdx.x;
  if (i < NNODES * 32) z[i] = mean32[i] + noise[i] * expf(lstd[i]);
}

// ---------------- seq_fts = features @ fc_w  [8192,256]x[256,32] ----------------

__global__ __launch_bounds__(256) void seq_kernel(const float* __restrict__ F, const float* __restrict__ Wf,
                                                  float* __restrict__ out) {
  int t = blockIdx.x * 256 + threadIdx.x;  // 65536 threads
  int row = t >> 3;
  int cq = (t & 7) * 4;
  float acc[4] = {0.f, 0.f, 0.f, 0.f};
  const float* frow = F + row * 256;
  for (int k = 0; k < 256; ++k) {
    float f = frow[k];
    float4 w = *(const float4*)(Wf + k * 32 + cq);
    acc[0] = fmaf(f, w.x, acc[0]);
    acc[1] = fmaf(f, w.y, acc[1]);
    acc[2] = fmaf(f, w.z, acc[2]);
    acc[3] = fmaf(f, w.w, acc[3]);
  }
  float4 o = {acc[0], acc[1], acc[2], acc[3]};
  *(float4*)&out[row * 32 + cq] = o;
}

// ---------------- adj = sigmoid(z @ z^T), z [8192][32] ----------------
// 128x128 tile per block; per-thread 8x8 split as {4ty,4ty+64} x {4tx,4tx+64}

__global__ __launch_bounds__(256) void adj_kernel(const float* __restrict__ z, float* __restrict__ out) {
  __shared__ __align__(16) float zr[32][132];
  __shared__ __align__(16) float zc[32][132];
  int tid = threadIdx.x;
  long rowBase = (long)blockIdx.y * 128;
  long colBase = (long)blockIdx.x * 128;
  {
    int m = tid >> 1;
    int k0 = (tid & 1) * 16;
    const float* srcR = z + (rowBase + m) * 32 + k0;
    const float* srcC = z + (colBase + m) * 32 + k0;
#pragma unroll
    for (int j = 0; j < 4; ++j) {
      float4 v = *(const float4*)(srcR + 4 * j);
      zr[k0 + 4 * j + 0][m] = v.x;
      zr[k0 + 4 * j + 1][m] = v.y;
      zr[k0 + 4 * j + 2][m] = v.z;
      zr[k0 + 4 * j + 3][m] = v.w;
      float4 w = *(const float4*)(srcC + 4 * j);
      zc[k0 + 4 * j + 0][m] = w.x;
      zc[k0 + 4 * j + 1][m] = w.y;
      zc[k0 + 4 * j + 2][m] = w.z;
      zc[k0 + 4 * j + 3][m] = w.w;
    }
  }
  __syncthreads();
  int tx = tid & 15, ty = tid >> 4;
  float acc[8][8] = {};
#pragma unroll 4
  for (int k = 0; k < 32; ++k) {
    float4 a0 = *(const float4*)&zr[k][4 * ty];
    float4 a1 = *(const float4*)&zr[k][4 * ty + 64];
    float4 b0 = *(const float4*)&zc[k][4 * tx];
    float4 b1 = *(const float4*)&zc[k][4 * tx + 64];
    float a[8] = {a0.x, a0.y, a0.z, a0.w, a1.x, a1.y, a1.z, a1.w};
    float b[8] = {b0.x, b0.y, b0.z, b0.w, b1.x, b1.y, b1.z, b1.w};
#pragma unroll
    for (int i = 0; i < 8; ++i)
#pragma unroll
      for (int j = 0; j < 8; ++j) acc[i][j] = fmaf(a[i], b[j], acc[i][j]);
  }
#pragma unroll
  for (int i = 0; i < 8; ++i) {
    long r = rowBase + 4 * ty + (i & 3) + (i >> 2) * 64;
    long cbase = colBase + 4 * tx + ((i >> 2) == 0 ? 0 : 0);  // cols handled by j split below
    float* op = out + r * 8192;
    float4 o0, o1;
    o0.x = 1.f / (1.f + __expf(-acc[i][0]));
    o0.y = 1.f / (1.f + __expf(-acc[i][1]));
    o0.z = 1.f / (1.f + __expf(-acc[i][2]));
    o0.w = 1.f / (1.f + __expf(-acc[i][3]));
    o1.x = 1.f / (1.f + __expf(-acc[i][4]));
    o1.y = 1.f / (1.f + __expf(-acc[i][5]));
    o1.z = 1.f / (1.f + __expf(-acc[i][6]));
    o1.w = 1.f / (1.f + __expf(-acc[i][7]));
    *(float4*)(op + colBase + 4 * tx) = o0;
    *(float4*)(op + colBase + 4 * tx + 64) = o1;
  }
}

// ---------------- launcher ----------------

extern "C" void kernel_launch(void* const* d_in, const int* in_sizes, int n_in,
                              void* d_out, int out_size, void* d_ws, size_t ws_size,
                              hipStream_t stream) {
  const float* features = (const float*)d_in[0];
  const float* noise    = (const float*)d_in[1];
  const int*   src      = (const int*)d_in[2];
  const int*   dst      = (const int*)d_in[3];
  const float* W1       = (const float*)d_in[4];
  const float* b1       = (const float*)d_in[5];
  const float* W2       = (const float*)d_in[6];
  const float* b2       = (const float*)d_in[7];
  const float* W3       = (const float*)d_in[8];
  const float* b3       = (const float*)d_in[9];
  const float* fcw      = (const float*)d_in[10];

  float* out = (float*)d_out;

  // ws layout (4B units)
  int* ws_i    = (int*)d_ws;
  int* out_deg = ws_i;                 // 8192
  int* in_deg  = ws_i + 8192;          // 8192
  int* row_ptr = ws_i + 16384;         // 8193
  int* cursor  = ws_i + 24832;         // 8192
  int* csr     = ws_i + 33024;         // 262144
  float* norm_src = (float*)(ws_i + 295168);  // 8192
  float* norm_dst = (float*)(ws_i + 303360);  // 8192

  // big intermediates live in the adj region of d_out (overwritten last by adj_kernel)
  float* adj    = out;
  float* zbuf   = out + NNOUT;             // final output z [8192*32]
  float* seq    = out + NNOUT + 262144;    // final output seq_fts [8192*32]
  float* bufQ   = out;                     // [8192*256]
  float* bufH   = out + 2097152;           // [8192*256]
  float* mean32 = out + 4194304;           // [8192*32]
  float* lstd   = out + 4456448;           // [8192*32]

  zero_kernel<<<64, 256, 0, stream>>>(out_deg, 16384);  // out_deg + in_deg
  deg_kernel<<<NEDGES / 256, 256, 0, stream>>>(src, dst, out_deg, in_deg);
  norm_kernel<<<NNODES / 256, 256, 0, stream>>>(out_deg, in_deg, norm_src, norm_dst);
  scan_kernel<<<1, 256, 0, stream>>>(in_deg, row_ptr, cursor);
  scatter_kernel<<<NEDGES / 256, 256, 0, stream>>>(src, dst, cursor, csr);

  // layer 1: Q1 = propagate(features); h1 = relu(Q1@W1 + b1)
  propagate_kernel<<<NNODES, 256, 0, stream>>>(features, bufQ, row_ptr, csr, norm_src, norm_dst);
  gemm_bias_relu<<<dim3(128, 4), 256, 0, stream>>>(bufQ, W1, b1, bufH);

  // layers 2+3 share: Q2 = propagate(h1); mean32/log_std = relu(Q2@[W2[:, :32] | W3] + b)
  propagate_kernel<<<NNODES, 256, 0, stream>>>(bufH, bufQ, row_ptr, csr, norm_src, norm_dst);
  gemm_z<<<128, 256, 0, stream>>>(bufQ, W2, b2, W3, b3, mean32, lstd);
  z_combine<<<1024, 256, 0, stream>>>(mean32, lstd, noise, zbuf);

  seq_kernel<<<256, 256, 0, stream>>>(features, fcw, seq);

  adj_kernel<<<dim3(64, 64), 256, 0, stream>>>(zbuf, adj);
}

// Round 3
// 218.855 us; speedup vs baseline: 1.3308x; 1.3308x over previous
//
#include <hip/hip_runtime.h>
#include <hip/hip_fp16.h>

#define NNODES 8192
#define NEDGES 262144
#define NNOUT 67108864L   // 8192*8192

typedef _Float16 half8 __attribute__((ext_vector_type(8)));
typedef _Float16 half4 __attribute__((ext_vector_type(4)));
typedef _Float16 half2v __attribute__((ext_vector_type(2)));
typedef float float4v __attribute__((ext_vector_type(4)));

// ---------------- graph preprocessing ----------------

__global__ __launch_bounds__(256) void zero_kernel(int* __restrict__ p, int n) {
  int i = blockIdx.x * 256 + threadIdx.x;
  if (i < n) p[i] = 0;
}

__global__ __launch_bounds__(256) void deg_kernel(const int* __restrict__ src, const int* __restrict__ dst,
                                                  int* __restrict__ out_deg, int* __restrict__ in_deg) {
  int e = blockIdx.x * 256 + threadIdx.x;
  if (e < NEDGES) {
    atomicAdd(&out_deg[src[e]], 1);
    atomicAdd(&in_deg[dst[e]], 1);
  }
}

// single block: scan in_deg -> row_ptr/cursor, and compute both degree norms
__global__ __launch_bounds__(256) void scan_norm_kernel(const int* __restrict__ in_deg,
                                                        const int* __restrict__ out_deg,
                                                        int* __restrict__ row_ptr, int* __restrict__ cursor,
                                                        float* __restrict__ norm_src, float* __restrict__ norm_dst) {
  __shared__ int partial[256];
  int t = threadIdx.x;
  int base = t * 32;
  int local[32];
  int s = 0;
#pragma unroll
  for (int i = 0; i < 32; ++i) { local[i] = in_deg[base + i]; s += local[i]; }
  partial[t] = s;
  __syncthreads();
  for (int off = 1; off < 256; off <<= 1) {
    int v = (t >= off) ? partial[t - off] : 0;
    __syncthreads();
    partial[t] += v;
    __syncthreads();
  }
  int run = (t == 0) ? 0 : partial[t - 1];
  if (t == 0) row_ptr[0] = 0;
#pragma unroll
  for (int i = 0; i < 32; ++i) {
    int od = out_deg[base + i]; if (od < 1) od = 1;
    int id = local[i]; if (id < 1) id = 1;
    norm_src[base + i] = rsqrtf((float)od);
    norm_dst[base + i] = rsqrtf((float)id);
    cursor[base + i] = run;
    run += local[i];
    row_ptr[base + i + 1] = run;
  }
}

__global__ __launch_bounds__(256) void scatter_kernel(const int* __restrict__ src, const int* __restrict__ dst,
                                                      int* __restrict__ cursor, int* __restrict__ csr) {
  int e = blockIdx.x * 256 + threadIdx.x;
  if (e < NEDGES) {
    int d = dst[e];
    int pos = atomicAdd(&cursor[d], 1);
    csr[pos] = src[e];
  }
}

// xs = (half)(features * norm_src[row])  [8192][256]
__global__ __launch_bounds__(256) void convert_xs(const float* __restrict__ x, const float* __restrict__ norm_src,
                                                  _Float16* __restrict__ xs) {
  int i = blockIdx.x * 256 + threadIdx.x;   // 524288 threads, 4 elems each
  int base = i * 4;
  float ns = norm_src[base >> 8];
  float4 v = *(const float4*)(x + base);
  half4 o = {(_Float16)(v.x * ns), (_Float16)(v.y * ns), (_Float16)(v.z * ns), (_Float16)(v.w * ns)};
  *(half4*)(xs + base) = o;
}

// ---------------- propagation: Q[v] = norm_dst[v] * sum_{e: dst=v} xs[src_e]  (xs pre-scaled fp16) ----------
// 2 nodes per block; 128 threads/node, 2 cols per thread

__global__ __launch_bounds__(256) void propagate_half(const _Float16* __restrict__ xs, float* __restrict__ Q,
                                                      const int* __restrict__ row_ptr, const int* __restrict__ csr,
                                                      const float* __restrict__ norm_dst) {
  int tid = threadIdx.x;
  int v = blockIdx.x * 2 + (tid >> 7);
  int j = tid & 127;
  int beg = row_ptr[v], end = row_ptr[v + 1];
  float ax = 0.f, ay = 0.f;
  int e = beg;
  for (; e + 4 <= end; e += 4) {
    int s0 = csr[e], s1 = csr[e + 1], s2 = csr[e + 2], s3 = csr[e + 3];
    half2v v0 = *(const half2v*)(xs + (long)s0 * 256 + 2 * j);
    half2v v1 = *(const half2v*)(xs + (long)s1 * 256 + 2 * j);
    half2v v2 = *(const half2v*)(xs + (long)s2 * 256 + 2 * j);
    half2v v3 = *(const half2v*)(xs + (long)s3 * 256 + 2 * j);
    ax += (float)v0.x + (float)v1.x + (float)v2.x + (float)v3.x;
    ay += (float)v0.y + (float)v1.y + (float)v2.y + (float)v3.y;
  }
  for (; e < end; ++e) {
    int s0 = csr[e];
    half2v v0 = *(const half2v*)(xs + (long)s0 * 256 + 2 * j);
    ax += (float)v0.x;
    ay += (float)v0.y;
  }
  float nd = norm_dst[v];
  float2 o = {ax * nd, ay * nd};
  *(float2*)&Q[(long)v * 256 + 2 * j] = o;
}

// ---------------- GEMM1: xs2 = (half)(relu(Q@W1 + b1) * norm_src[row]) ----------------

__global__ __launch_bounds__(256) void gemm_bias_relu_h(const float* __restrict__ A, const float* __restrict__ B,
                                                        const float* __restrict__ bias,
                                                        const float* __restrict__ norm_src,
                                                        _Float16* __restrict__ xs) {
  __shared__ __align__(16) float As[64][68];
  __shared__ __align__(16) float Bs[64][68];
  int tid = threadIdx.x;
  int tx = tid & 15, ty = tid >> 4;
  int rowBase = blockIdx.x * 64;
  int colBase = blockIdx.y * 64;
  float acc[4][4] = {};
  for (int kb = 0; kb < 256; kb += 64) {
    {
      int m = tid >> 2;
      int k0 = (tid & 3) * 16;
      const float* s0 = A + (rowBase + m) * 256 + kb + k0;
#pragma unroll
      for (int j = 0; j < 4; ++j) {
        float4 v = *(const float4*)(s0 + 4 * j);
        As[k0 + 4 * j + 0][m] = v.x;
        As[k0 + 4 * j + 1][m] = v.y;
        As[k0 + 4 * j + 2][m] = v.z;
        As[k0 + 4 * j + 3][m] = v.w;
      }
      int k = tid >> 2;
      int c0 = (tid & 3) * 16;
      const float* s1 = B + (kb + k) * 256 + colBase + c0;
#pragma unroll
      for (int j = 0; j < 4; ++j)
        *(float4*)&Bs[k][c0 + 4 * j] = *(const float4*)(s1 + 4 * j);
    }
    __syncthreads();
#pragma unroll 8
    for (int kk = 0; kk < 64; ++kk) {
      float4 av = *(const float4*)&As[kk][4 * ty];
      float4 bv = *(const float4*)&Bs[kk][4 * tx];
      float a[4] = {av.x, av.y, av.z, av.w};
      float b[4] = {bv.x, bv.y, bv.z, bv.w};
#pragma unroll
      for (int i = 0; i < 4; ++i)
#pragma unroll
        for (int j = 0; j < 4; ++j) acc[i][j] = fmaf(a[i], b[j], acc[i][j]);
    }
    __syncthreads();
  }
  float4 bv = *(const float4*)(bias + colBase + 4 * tx);
  float bb[4] = {bv.x, bv.y, bv.z, bv.w};
#pragma unroll
  for (int i = 0; i < 4; ++i) {
    int r = rowBase + 4 * ty + i;
    float ns = norm_src[r];
    half4 o = {(_Float16)(fmaxf(acc[i][0] + bb[0], 0.f) * ns),
               (_Float16)(fmaxf(acc[i][1] + bb[1], 0.f) * ns),
               (_Float16)(fmaxf(acc[i][2] + bb[2], 0.f) * ns),
               (_Float16)(fmaxf(acc[i][3] + bb[3], 0.f) * ns)};
    *(half4*)&xs[(long)r * 256 + colBase + 4 * tx] = o;
  }
}

// ---------------- fused mean/log_std GEMM + z combine + fp16 hi/lo split ----------------
// cols 0..31: W2[:, :32] (+b2) -> mean; cols 32..63: W3 (+b3) -> log_std
// z = mean + noise * exp(log_std); write z (f32 out), Zh, Zl (fp16 hi/lo)

__global__ __launch_bounds__(256) void gemm_z(const float* __restrict__ A, const float* __restrict__ W2,
                                              const float* __restrict__ b2, const float* __restrict__ W3,
                                              const float* __restrict__ b3, const float* __restrict__ noise,
                                              float* __restrict__ zout, _Float16* __restrict__ Zh,
                                              _Float16* __restrict__ Zl) {
  __shared__ __align__(16) float As[64][68];
  __shared__ __align__(16) float Bs[64][68];
  __shared__ float sm[64][65];
  int tid = threadIdx.x;
  int tx = tid & 15, ty = tid >> 4;
  int rowBase = blockIdx.x * 64;
  float acc[4][4] = {};
  for (int kb = 0; kb < 256; kb += 64) {
    {
      int m = tid >> 2;
      int k0 = (tid & 3) * 16;
      const float* s0 = A + (rowBase + m) * 256 + kb + k0;
#pragma unroll
      for (int j = 0; j < 4; ++j) {
        float4 v = *(const float4*)(s0 + 4 * j);
        As[k0 + 4 * j + 0][m] = v.x;
        As[k0 + 4 * j + 1][m] = v.y;
        As[k0 + 4 * j + 2][m] = v.z;
        As[k0 + 4 * j + 3][m] = v.w;
      }
      int k = tid >> 2;
      int c0 = (tid & 3) * 16;
      const float* s1 = (c0 < 32) ? (W2 + (kb + k) * 256 + c0) : (W3 + (kb + k) * 32 + (c0 - 32));
#pragma unroll
      for (int j = 0; j < 4; ++j)
        *(float4*)&Bs[k][c0 + 4 * j] = *(const float4*)(s1 + 4 * j);
    }
    __syncthreads();
#pragma unroll 8
    for (int kk = 0; kk < 64; ++kk) {
      float4 av = *(const float4*)&As[kk][4 * ty];
      float4 bv = *(const float4*)&Bs[kk][4 * tx];
      float a[4] = {av.x, av.y, av.z, av.w};
      float b[4] = {bv.x, bv.y, bv.z, bv.w};
#pragma unroll
      for (int i = 0; i < 4; ++i)
#pragma unroll
        for (int j = 0; j < 4; ++j) acc[i][j] = fmaf(a[i], b[j], acc[i][j]);
    }
    __syncthreads();
  }
  int c = 4 * tx;
  const float* bp = (c < 32) ? (b2 + c) : (b3 + (c - 32));
  float4 bv = *(const float4*)bp;
  float bb[4] = {bv.x, bv.y, bv.z, bv.w};
#pragma unroll
  for (int i = 0; i < 4; ++i) {
#pragma unroll
    for (int j = 0; j < 4; ++j) sm[4 * ty + i][c + j] = fmaxf(acc[i][j] + bb[j], 0.f);
  }
  __syncthreads();
  // z combine: 64 rows x 32 cols = 2048 elems, 8 per thread
  int r = tid >> 2;
  int cb = (tid & 3) * 8;
  long gr = rowBase + r;
  float4 n0 = *(const float4*)(noise + gr * 32 + cb);
  float4 n1 = *(const float4*)(noise + gr * 32 + cb + 4);
  float nz[8] = {n0.x, n0.y, n0.z, n0.w, n1.x, n1.y, n1.z, n1.w};
  float zv[8];
#pragma unroll
  for (int j = 0; j < 8; ++j) {
    float m = sm[r][cb + j];
    float ls = sm[r][32 + cb + j];
    zv[j] = m + nz[j] * expf(ls);
  }
  *(float4*)(zout + gr * 32 + cb) = make_float4(zv[0], zv[1], zv[2], zv[3]);
  *(float4*)(zout + gr * 32 + cb + 4) = make_float4(zv[4], zv[5], zv[6], zv[7]);
  half8 hh, hl;
#pragma unroll
  for (int j = 0; j < 8; ++j) {
    _Float16 h = (_Float16)zv[j];
    hh[j] = h;
    hl[j] = (_Float16)(zv[j] - (float)h);
  }
  *(half8*)(Zh + gr * 32 + cb) = hh;
  *(half8*)(Zl + gr * 32 + cb) = hl;
}

// ---------------- seq_fts = features @ fc_w  [8192,256]x[256,32] ----------------

__global__ __launch_bounds__(256) void seq_kernel(const float* __restrict__ F, const float* __restrict__ Wf,
                                                  float* __restrict__ out) {
  int t = blockIdx.x * 256 + threadIdx.x;  // 65536 threads
  int row = t >> 3;
  int cq = (t & 7) * 4;
  float acc[4] = {0.f, 0.f, 0.f, 0.f};
  const float* frow = F + row * 256;
  for (int k = 0; k < 256; ++k) {
    float f = frow[k];
    float4 w = *(const float4*)(Wf + k * 32 + cq);
    acc[0] = fmaf(f, w.x, acc[0]);
    acc[1] = fmaf(f, w.y, acc[1]);
    acc[2] = fmaf(f, w.z, acc[2]);
    acc[3] = fmaf(f, w.w, acc[3]);
  }
  float4 o = {acc[0], acc[1], acc[2], acc[3]};
  *(float4*)&out[row * 32 + cq] = o;
}

// ---------------- adj = sigmoid(Z @ Z^T) via MFMA fp16 hi/lo split ----------------
// Z = Zh + Zl (fp16 pair); Z@Z^T ~= Zh Zh^T + Zh Zl^T + Zl Zh^T  (error ~2^-22)
// block: 128x128 tile, 4 waves, wave w owns rows [w*32, w*32+32)

__global__ __launch_bounds__(256) void adj_mfma(const _Float16* __restrict__ Zh, const _Float16* __restrict__ Zl,
                                                float* __restrict__ out) {
  int tid = threadIdx.x;
  int wave = tid >> 6;
  int lane = tid & 63;
  long rowBase = (long)blockIdx.y * 128 + wave * 32;
  long colBase = (long)blockIdx.x * 128;
  int l15 = lane & 15;
  int lk = (lane >> 4) * 8;
  // A fragments for two 16-row tiles (A[m][k]: m = lane&15, k = (lane>>4)*8 + j)
  half8 ah0 = *(const half8*)(Zh + (rowBase + l15) * 32 + lk);
  half8 al0 = *(const half8*)(Zl + (rowBase + l15) * 32 + lk);
  half8 ah1 = *(const half8*)(Zh + (rowBase + 16 + l15) * 32 + lk);
  half8 al1 = *(const half8*)(Zl + (rowBase + 16 + l15) * 32 + lk);
  int crow = (lane >> 4) * 4;
#pragma unroll
  for (int ct = 0; ct < 8; ++ct) {
    // B fragment (B[k][n]: n = lane&15 -> Z row colBase+ct*16+n, same layout as A)
    half8 bh = *(const half8*)(Zh + (colBase + ct * 16 + l15) * 32 + lk);
    half8 bl = *(const half8*)(Zl + (colBase + ct * 16 + l15) * 32 + lk);
    float4v acc0 = {}, acc1 = {};
    acc0 = __builtin_amdgcn_mfma_f32_16x16x32_f16(al0, bh, acc0, 0, 0, 0);
    acc0 = __builtin_amdgcn_mfma_f32_16x16x32_f16(ah0, bl, acc0, 0, 0, 0);
    acc0 = __builtin_amdgcn_mfma_f32_16x16x32_f16(ah0, bh, acc0, 0, 0, 0);
    acc1 = __builtin_amdgcn_mfma_f32_16x16x32_f16(al1, bh, acc1, 0, 0, 0);
    acc1 = __builtin_amdgcn_mfma_f32_16x16x32_f16(ah1, bl, acc1, 0, 0, 0);
    acc1 = __builtin_amdgcn_mfma_f32_16x16x32_f16(ah1, bh, acc1, 0, 0, 0);
    long c = colBase + ct * 16 + l15;
    // C/D layout: col = lane&15, row = (lane>>4)*4 + reg
#pragma unroll
    for (int r = 0; r < 4; ++r) {
      out[(rowBase + crow + r) * 8192 + c] = 1.f / (1.f + __expf(-acc0[r]));
      out[(rowBase + 16 + crow + r) * 8192 + c] = 1.f / (1.f + __expf(-acc1[r]));
    }
  }
}

// ---------------- launcher ----------------

extern "C" void kernel_launch(void* const* d_in, const int* in_sizes, int n_in,
                              void* d_out, int out_size, void* d_ws, size_t ws_size,
                              hipStream_t stream) {
  const float* features = (const float*)d_in[0];
  const float* noise    = (const float*)d_in[1];
  const int*   src      = (const int*)d_in[2];
  const int*   dst      = (const int*)d_in[3];
  const float* W1       = (const float*)d_in[4];
  const float* b1       = (const float*)d_in[5];
  const float* W2       = (const float*)d_in[6];
  const float* b2       = (const float*)d_in[7];
  const float* W3       = (const float*)d_in[8];
  const float* b3       = (const float*)d_in[9];
  const float* fcw      = (const float*)d_in[10];

  float* out = (float*)d_out;

  // ws layout (4B units): ~2.3 MB total
  int* ws_i    = (int*)d_ws;
  int* out_deg = ws_i;                 // 8192
  int* in_deg  = ws_i + 8192;          // 8192
  int* row_ptr = ws_i + 16384;         // 8193
  int* cursor  = ws_i + 24832;         // 8192
  int* csr     = ws_i + 33024;         // 262144
  float* norm_src = (float*)(ws_i + 295168);  // 8192
  float* norm_dst = (float*)(ws_i + 303360);  // 8192
  _Float16* Zh = (_Float16*)(ws_i + 311552);  // 262144 halves = 131072 words
  _Float16* Zl = (_Float16*)(ws_i + 442624);  // 262144 halves

  // big intermediates live in the adj region of d_out (overwritten last by adj)
  float* adj      = out;
  float* zbuf     = out + NNOUT;             // final output z [8192*32]
  float* seq      = out + NNOUT + 262144;    // final output seq_fts [8192*32]
  float* bufQ     = out;                     // f32 [8192*256] = 2M floats
  _Float16* xs    = (_Float16*)(out + 2097152);  // fp16 [8192*256] = 1M floats region

  zero_kernel<<<64, 256, 0, stream>>>(out_deg, 16384);  // out_deg + in_deg
  deg_kernel<<<NEDGES / 256, 256, 0, stream>>>(src, dst, out_deg, in_deg);
  scan_norm_kernel<<<1, 256, 0, stream>>>(in_deg, out_deg, row_ptr, cursor, norm_src, norm_dst);
  scatter_kernel<<<NEDGES / 256, 256, 0, stream>>>(src, dst, cursor, csr);

  // layer 1
  convert_xs<<<2048, 256, 0, stream>>>(features, norm_src, xs);
  propagate_half<<<NNODES / 2, 256, 0, stream>>>(xs, bufQ, row_ptr, csr, norm_dst);
  gemm_bias_relu_h<<<dim3(128, 4), 256, 0, stream>>>(bufQ, W1, b1, norm_src, xs);

  // layers 2+3 share one propagation
  propagate_half<<<NNODES / 2, 256, 0, stream>>>(xs, bufQ, row_ptr, csr, norm_dst);
  gemm_z<<<128, 256, 0, stream>>>(bufQ, W2, b2, W3, b3, noise, zbuf, Zh, Zl);

  seq_kernel<<<256, 256, 0, stream>>>(features, fcw, seq);

  adj_mfma<<<dim3(64, 64), 256, 0, stream>>>(Zh, Zl, adj);
}